// Round 5
// baseline (6341.874 us; speedup 1.0000x reference)
//
#include <hip/hip_runtime.h>

#define B_ 16
#define T_ 64
#define C_ 4
#define H_ 129
#define W_ 2
#define HID_ 32
#define R_ 9
#define NCHUNK_ 15                    // ceil(129/9)
#define NBLK_ (B_*NCHUNK_)            // 240 blocks
#define SB_ (B_*HID_*H_*W_)           // 132096 floats per state buffer

__device__ __forceinline__ float sigf(float x)   { return 1.0f / (1.0f + __expf(-x)); }
__device__ __forceinline__ float tanhf_(float x) { return 1.0f - 2.0f / (1.0f + __expf(2.0f * x)); }

// Pre-transpose conv weights to [ic][kh][oc] (coalesced per-wave weight loads)
// and fc1_w to [j][o] (coalesced head GEMV).
__global__ __launch_bounds__(256) void init_kernel(
    const float* __restrict__ w0, const float* __restrict__ w1,
    const float* __restrict__ fc1w,
    float* __restrict__ W0T, float* __restrict__ W1T, float* __restrict__ FC1T)
{
  int i = blockIdx.x * 256 + threadIdx.x;
  if (i < 36 * 3 * 128) {
    int ic = i / (3 * 128), kh = (i / 128) % 3, oc = i % 128;
    W0T[i] = w0[(oc * 36 + ic) * 3 + kh];
  }
  int j = i - 36 * 3 * 128;
  if (j >= 0 && j < 64 * 3 * 128) {
    int ic = j / (3 * 128), kh = (j / 128) % 3, oc = j % 128;
    W1T[j] = w1[(oc * 64 + ic) * 3 + kh];
  }
  int k = i - 36 * 3 * 128 - 64 * 3 * 128;
  if (k >= 0 && k < 258 * 256) {
    int jj = k / 256, o = k % 256;
    FC1T[k] = fc1w[o * 258 + jj];
  }
}

// conv0: z rows R0..R0+5 (absolute z-row zr_abs = R0+r, global row own0-1+zr_abs).
// in0 float tr corresponds to global row own0-2+tr; z row needs tr = zr_abs+kh.
template<int R0>
__device__ __forceinline__ void conv0_half(
    const float (&in0)[36][2][16], const float* __restrict__ W0T, float bv,
    int cc, int oc, float (&zt)[2][11][128])
{
  float acc[6];
  #pragma unroll
  for (int r = 0; r < 6; ++r) acc[r] = bv;
  #pragma unroll 4
  for (int ic = 0; ic < 36; ++ic) {
    float inv[12];
    const float4* p = (const float4*)&in0[ic][cc][0];
    if (R0 == 0) {
      *(float4*)&inv[0] = p[0];            // floats 0..7
      *(float4*)&inv[4] = p[1];
    } else {
      *(float4*)&inv[0] = p[1];            // floats 4..15
      *(float4*)&inv[4] = p[2];
      *(float4*)&inv[8] = p[3];
    }
    const float* wp = W0T + ic * 384 + oc;
    #pragma unroll
    for (int kh = 0; kh < 3; ++kh) {
      float w = wp[kh * 128];
      #pragma unroll
      for (int r = 0; r < 6; ++r)
        acc[r] = fmaf(w, inv[R0 + r + kh - (R0 ? 4 : 0)], acc[r]);
    }
  }
  #pragma unroll
  for (int r = 0; r < 6; ++r)
    if (R0 == 0 || r > 0) zt[cc][R0 + r][oc] = acc[r];  // skip dup row (identical value anyway)
}

// conv1: z rows R0..R0+4 (global row own0+zr_abs); in1 tr = global row own0-1+tr.
template<int R0>
__device__ __forceinline__ void conv1_half(
    const float (&in1)[64][2][16], const float* __restrict__ W1T, float bv,
    int cc, int oc, float (&zt)[2][11][128])
{
  float acc[5];
  #pragma unroll
  for (int r = 0; r < 5; ++r) acc[r] = bv;
  #pragma unroll 4
  for (int ic = 0; ic < 64; ++ic) {
    float inv[8];
    const float4* p = (const float4*)&in1[ic][cc][0];
    if (R0 == 0) { *(float4*)&inv[0] = p[0]; *(float4*)&inv[4] = p[1]; }   // floats 0..7
    else         { *(float4*)&inv[0] = p[1]; *(float4*)&inv[4] = p[2]; }   // floats 4..11
    const float* wp = W1T + ic * 384 + oc;
    #pragma unroll
    for (int kh = 0; kh < 3; ++kh) {
      float w = wp[kh * 128];
      #pragma unroll
      for (int r = 0; r < 5; ++r)
        acc[r] = fmaf(w, inv[r + kh], acc[r]);   // tr-index = R0+r+kh; array holds floats R0.. so idx r+kh
    }
  }
  #pragma unroll
  for (int r = 0; r < 5; ++r)
    if (R0 == 0 || r > 0) zt[cc][R0 + r][oc] = acc[r];
}

// Persistent ConvLSTM: all 64 steps in one cooperative launch.
// Grid 240 blocks x 512 threads; block owns rows [own0,own1) of one sample.
// Cross-block halo via global ping-pong state + per-block step flags
// (acquire/release, agent scope). Max neighbor skew = 1 step -> 2 buffers safe.
__global__ __launch_bounds__(512, 2) void persist_kernel(
    const float* __restrict__ x, const int* __restrict__ lens,
    const float* __restrict__ W0T, const float* __restrict__ b0,
    const float* __restrict__ W1T, const float* __restrict__ b1,
    float* __restrict__ h0p0, float* __restrict__ h0p1,
    float* __restrict__ c0p0, float* __restrict__ c0p1,
    float* __restrict__ h1p0, float* __restrict__ h1p1,
    float* __restrict__ c1, float* __restrict__ hlast,
    int* __restrict__ flags)
{
  __shared__ float in0[36][2][16];   // concat(x_t, h0) rows own0-2 .. own0+10
  __shared__ float in1[64][2][16];   // concat(h0_new, h1) rows own0-1 .. own0+9
  __shared__ float zt[2][11][128];   // conv output [cc][zrow][oc]: stride-1 in oc

  const int tid   = threadIdx.x;
  const int blk   = blockIdx.x;
  const int b     = blk / NCHUNK_;
  const int chunk = blk % NCHUNK_;
  const int own0  = chunk * R_;
  const int own1  = min(own0 + R_, H_);
  const int zhi   = min(own1 + 1, H_);
  const int oc    = tid & 127;
  const int cc    = (tid >> 7) & 1;
  const int rh    = tid >> 8;        // row-half: 0 or 1
  const int len   = lens[b];
  const float bv0 = b0[oc];
  const float bv1 = b1[oc];

  for (int t = 0; t < T_; ++t) {
    const float *h0i, *c0i, *h1i;
    float *h0o, *c0o, *h1o;
    if ((t & 1) == 0) { h0i = h0p1; c0i = c0p1; h1i = h1p1; h0o = h0p0; c0o = c0p0; h1o = h1p0; }
    else              { h0i = h0p0; c0i = c0p0; h1i = h1p0; h0o = h0p1; c0o = c0p1; h1o = h1p1; }

    // ---- wait for neighbors to finish step t-1 (publishes their state + frees
    //      the buffer we are about to overwrite)
    if (t > 0) {
      if (tid == 0 && chunk > 0) {
        while (__hip_atomic_load(&flags[blk - 1], __ATOMIC_ACQUIRE, __HIP_MEMORY_SCOPE_AGENT) < t)
          __builtin_amdgcn_s_sleep(1);
      }
      if (tid == 1 && chunk < NCHUNK_ - 1) {
        while (__hip_atomic_load(&flags[blk + 1], __ATOMIC_ACQUIRE, __HIP_MEMORY_SCOPE_AGENT) < t)
          __builtin_amdgcn_s_sleep(1);
      }
    }
    __syncthreads();

    // ---- stage in0 (x + h0_old, 13 rows, zero-padded) and in1 h1-part (11 rows)
    for (int l = tid; l < 36 * 26; l += 512) {
      int ic = l / 26, rem = l % 26, tr = rem >> 1, c2 = rem & 1;
      int gr = own0 - 2 + tr;
      float v = 0.f;
      if (gr >= 0 && gr < H_) {
        v = (ic < C_) ? x[((b * T_ + t) * C_ + ic) * H_ * W_ + gr * W_ + c2]
                      : h0i[((b * HID_ + (ic - C_)) * H_ + gr) * W_ + c2];
      }
      in0[ic][c2][tr] = v;
    }
    for (int l = tid; l < 64 * 22; l += 512) {
      int ic = l / 22, rem = l % 22, tr = rem >> 1, c2 = rem & 1;
      int gr = own0 - 1 + tr;
      float v = 0.f;
      if (ic >= HID_ && gr >= 0 && gr < H_)
        v = h1i[((b * HID_ + (ic - HID_)) * H_ + gr) * W_ + c2];
      in1[ic][c2][tr] = v;
    }
    __syncthreads();

    // ---- conv0 (z rows 0..10 <-> global own0-1+zr)
    if (rh == 0) conv0_half<0>(in0, W0T, bv0, cc, oc, zt);
    else         conv0_half<5>(in0, W0T, bv0, cc, oc, zt);
    __syncthreads();

    // ---- gate0: rows own0-1 .. zhi-1 (halo rows stay in LDS only)
    for (int it = tid; it < 32 * 22; it += 512) {
      int hid = it & 31, rc = it >> 5;
      int r = rc >> 1, c2 = rc & 1;
      int zr = own0 - 1 + r;
      if (zr >= 0 && zr < zhi) {
        float zi = zt[c2][r][hid],      zf = zt[c2][r][hid + 32];
        float zo = zt[c2][r][hid + 64], zg = zt[c2][r][hid + 96];
        int cidx = ((b * HID_ + hid) * H_ + zr) * W_ + c2;
        float cp = c0i[cidx];
        float cn = sigf(zf) * cp + sigf(zi) * tanhf_(zg);
        float hn = sigf(zo) * tanhf_(cn);
        in1[hid][c2][r] = hn;
        if (zr >= own0 && zr < own1) { c0o[cidx] = cn; h0o[cidx] = hn; }
      }
    }
    __syncthreads();

    // ---- conv1 (z rows 0..8 <-> global own0+zr)
    if (rh == 0) conv1_half<0>(in1, W1T, bv1, cc, oc, zt);
    else         conv1_half<4>(in1, W1T, bv1, cc, oc, zt);
    __syncthreads();

    // ---- gate1: owned rows; capture h_last at t == len-1
    for (int it = tid; it < 32 * 18; it += 512) {
      int hid = it & 31, rc = it >> 5;
      int r = rc >> 1, c2 = rc & 1;
      if (r < own1 - own0) {
        int zr = own0 + r;
        float zi = zt[c2][r][hid],      zf = zt[c2][r][hid + 32];
        float zo = zt[c2][r][hid + 64], zg = zt[c2][r][hid + 96];
        int cidx = ((b * HID_ + hid) * H_ + zr) * W_ + c2;
        float cp = c1[cidx];
        float cn = sigf(zf) * cp + sigf(zi) * tanhf_(zg);
        float hn = sigf(zo) * tanhf_(cn);
        c1[cidx] = cn;
        h1o[cidx] = hn;
        if (t == len - 1)
          hlast[(b * HID_ + hid) * H_ * W_ + zr * W_ + c2] = hn;
      }
    }

    // ---- publish step t
    __threadfence();          // agent-scope: make this thread's writes visible
    __syncthreads();          // all threads fenced before the flag store
    if (tid == 0)
      __hip_atomic_store(&flags[blk], t + 1, __ATOMIC_RELEASE, __HIP_MEMORY_SCOPE_AGENT);
  }
}

// nin (1x1 conv over HID) -> fc1 -> fc2. One block per sample.
__global__ __launch_bounds__(256) void head_kernel(
    const float* __restrict__ hlast,
    const float* __restrict__ ninw, const float* __restrict__ ninb,
    const float* __restrict__ FC1T, const float* __restrict__ fc1b,
    const float* __restrict__ fc2w, const float* __restrict__ fc2b,
    float* __restrict__ out)
{
  __shared__ float lin[258];
  __shared__ float o1[256];
  int b = blockIdx.x, tid = threadIdx.x;
  for (int j = tid; j < 258; j += 256) {
    float s = ninb[0];
    #pragma unroll
    for (int h = 0; h < 32; ++h) s = fmaf(ninw[h], hlast[(b * 32 + h) * 258 + j], s);
    lin[j] = s;
  }
  __syncthreads();
  {
    float a = fc1b[tid];
    for (int j = 0; j < 258; ++j) a = fmaf(lin[j], FC1T[j * 256 + tid], a);
    o1[tid] = a;
  }
  __syncthreads();
  if (tid < 2) {
    float s = fc2b[tid];
    for (int k2 = 0; k2 < 256; ++k2) s = fmaf(o1[k2], fc2w[tid * 256 + k2], s);
    out[b * 2 + tid] = s;
  }
}

extern "C" void kernel_launch(void* const* d_in, const int* in_sizes, int n_in,
                              void* d_out, int out_size, void* d_ws, size_t ws_size,
                              hipStream_t stream) {
  const float* x     = (const float*)d_in[0];
  const int*   lens  = (const int*)  d_in[1];
  const float* w0    = (const float*)d_in[2];
  const float* b0    = (const float*)d_in[3];
  const float* w1    = (const float*)d_in[4];
  const float* b1    = (const float*)d_in[5];
  const float* ninw  = (const float*)d_in[6];
  const float* ninb  = (const float*)d_in[7];
  const float* fc1w  = (const float*)d_in[8];
  const float* fc1b  = (const float*)d_in[9];
  const float* fc2w  = (const float*)d_in[10];
  const float* fc2b  = (const float*)d_in[11];
  float* out = (float*)d_out;
  float* ws  = (float*)d_ws;

  const size_t SB = (size_t)SB_;
  // zeroed region: [h0p1, c0p1, h1p1, c1, flags] (initial state = 0, flags = 0)
  float* h0p1  = ws;
  float* c0p1  = h0p1 + SB;
  float* h1p1  = c0p1 + SB;
  float* c1    = h1p1 + SB;
  int*   flags = (int*)(c1 + SB);          // 256 ints
  float* h0p0  = (float*)(flags + 256);
  float* c0p0  = h0p0 + SB;
  float* h1p0  = c0p0 + SB;
  float* hlast = h1p0 + SB;
  float* W0T   = hlast + SB;               // 36*3*128
  float* W1T   = W0T + 36 * 3 * 128;       // 64*3*128
  float* FC1T  = W1T + 64 * 3 * 128;       // 258*256

  hipMemsetAsync(ws, 0, (4 * SB + 256) * sizeof(float), stream);
  init_kernel<<<408, 256, 0, stream>>>(w0, w1, fc1w, W0T, W1T, FC1T);

  void* args[] = { (void*)&x, (void*)&lens, (void*)&W0T, (void*)&b0, (void*)&W1T, (void*)&b1,
                   (void*)&h0p0, (void*)&h0p1, (void*)&c0p0, (void*)&c0p1,
                   (void*)&h1p0, (void*)&h1p1, (void*)&c1, (void*)&hlast, (void*)&flags };
  hipLaunchCooperativeKernel((void*)persist_kernel, dim3(NBLK_), dim3(512), args, 0, stream);

  head_kernel<<<B_, 256, 0, stream>>>(hlast, ninw, ninb, FC1T, fc1b, fc2w, fc2b, out);
}

// Round 6
// 962.116 us; speedup vs baseline: 6.5916x; 6.5916x over previous
//
#include <hip/hip_runtime.h>

#define B_ 16
#define T_ 64
#define C_ 4
#define H_ 129
#define W_ 2
#define HID_ 32
#define R_ 9
#define NCHUNK_ 15                    // ceil(129/9)
#define NL_ (B_*NCHUNK_)              // 240 blocks per layer role
#define SB_ (B_*HID_*H_*W_)           // 132096 floats per state buffer

__device__ __forceinline__ float sigf(float x)   { return 1.0f / (1.0f + __expf(-x)); }
__device__ __forceinline__ float tanhf_(float x) { return 1.0f - 2.0f / (1.0f + __expf(2.0f * x)); }

// Pre-transpose conv weights to [ic][kh][oc] (coalesced per-wave weight loads)
// and fc1_w to [j][o] (coalesced head GEMV).
__global__ __launch_bounds__(256) void init_kernel(
    const float* __restrict__ w0, const float* __restrict__ w1,
    const float* __restrict__ fc1w,
    float* __restrict__ W0T, float* __restrict__ W1T, float* __restrict__ FC1T)
{
  int i = blockIdx.x * 256 + threadIdx.x;
  if (i < 36 * 3 * 128) {
    int ic = i / (3 * 128), kh = (i / 128) % 3, oc = i % 128;
    W0T[i] = w0[(oc * 36 + ic) * 3 + kh];
  }
  int j = i - 36 * 3 * 128;
  if (j >= 0 && j < 64 * 3 * 128) {
    int ic = j / (3 * 128), kh = (j / 128) % 3, oc = j % 128;
    W1T[j] = w1[(oc * 64 + ic) * 3 + kh];
  }
  int k = i - 36 * 3 * 128 - 64 * 3 * 128;
  if (k >= 0 && k < 258 * 256) {
    int jj = k / 256, o = k % 256;
    FC1T[k] = fc1w[o * 258 + jj];
  }
}

// Conv over staged LDS input rows (row stride 12 floats, tr <-> global own0-1+tr).
// Computes z rows R0..R0+NR-1 (z row r <-> global own0+r), needs tr = r+kh.
// R0==0: inv holds floats 0..7  -> idx = r+kh      (max 6)
// R0==5: inv holds floats 4..11 -> idx = 1+r+kh    (max 6)
template<int NIC, int R0, int NR>
__device__ __forceinline__ void convT(
    const float* __restrict__ inb, const float* __restrict__ WT, float bv,
    int cc, int oc, float (*__restrict__ zt)[9][128])
{
  float acc[NR];
  #pragma unroll
  for (int r = 0; r < NR; ++r) acc[r] = bv;
  #pragma unroll 4
  for (int ic = 0; ic < NIC; ++ic) {
    const float4* p = (const float4*)(inb + ic * 24 + cc * 12);
    float inv[8];
    if (R0 == 0) { *(float4*)&inv[0] = p[0]; *(float4*)&inv[4] = p[1]; }
    else         { *(float4*)&inv[0] = p[1]; *(float4*)&inv[4] = p[2]; }
    const float* wp = WT + ic * 384 + oc;
    #pragma unroll
    for (int kh = 0; kh < 3; ++kh) {
      float w = wp[kh * 128];
      #pragma unroll
      for (int r = 0; r < NR; ++r)
        acc[r] = fmaf(w, inv[(R0 ? 1 : 0) + r + kh], acc[r]);
    }
  }
  #pragma unroll
  for (int r = 0; r < NR; ++r) zt[cc][R0 + r][oc] = acc[r];
}

// Launch k: blocks [0,NL_) run layer0 step k; blocks [NL_,2*NL_) run layer1 step k-1.
// Layer1@s needs only layer0@s output (previous launch) -> stream order is the barrier.
__global__ __launch_bounds__(512, 2) void step_kernel(
    const float* __restrict__ x, const int* __restrict__ lens,
    const float* __restrict__ W0T, const float* __restrict__ b0,
    const float* __restrict__ W1T, const float* __restrict__ b1,
    const float* __restrict__ h0r, float* __restrict__ h0w,
    const float* __restrict__ h1r, float* __restrict__ h1w,
    float* __restrict__ c0, float* __restrict__ c1,
    float* __restrict__ hlast, int k)
{
  __shared__ float smem[3840];                 // zt 2*9*128 = 2304 | inbuf <= 64*2*12 = 1536
  float (*zt)[9][128] = reinterpret_cast<float(*)[9][128]>(smem);
  float* inb = smem + 2304;

  const int tid  = threadIdx.x;
  const bool isL0 = blockIdx.x < NL_;
  const int lb   = isL0 ? blockIdx.x : blockIdx.x - NL_;
  const int b    = lb / NCHUNK_;
  const int chunk= lb % NCHUNK_;
  const int own0 = chunk * R_;
  const int own1 = min(own0 + R_, H_);
  const int nz   = own1 - own0;
  const int oc   = tid & 127;
  const int cc   = (tid >> 7) & 1;
  const int rh   = tid >> 8;                   // row-half 0/1

  if (isL0) {
    if (k >= T_) return;                       // k==T_: layer0 has no step
    // ---- stage in0: concat(x@k, h0@k-1), rows own0-1..own0+9 (tr 0..10), zero-pad
    for (int l = tid; l < 36 * 22; l += 512) {
      int ic = l / 22, rem = l % 22, tr = rem >> 1, c2 = rem & 1;
      int gr = own0 - 1 + tr;
      float v = 0.f;
      if (gr >= 0 && gr < H_)
        v = (ic < C_) ? x[((b * T_ + k) * C_ + ic) * H_ * W_ + gr * W_ + c2]
                      : h0r[((b * HID_ + (ic - C_)) * H_ + gr) * W_ + c2];
      inb[ic * 24 + c2 * 12 + tr] = v;
    }
    __syncthreads();
    if (rh == 0) convT<36, 0, 5>(inb, W0T, b0[oc], cc, oc, zt);
    else         convT<36, 5, 4>(inb, W0T, b0[oc], cc, oc, zt);
    __syncthreads();
    // ---- gate0: own rows only; c0 in-place (thread-local RMW)
    for (int it = tid; it < 32 * 18; it += 512) {
      int hid = it & 31, rc = it >> 5;
      int r = rc >> 1, c2 = rc & 1;
      if (r < nz) {
        float zi = zt[c2][r][hid],      zf = zt[c2][r][hid + 32];
        float zo = zt[c2][r][hid + 64], zg = zt[c2][r][hid + 96];
        int cidx = ((b * HID_ + hid) * H_ + own0 + r) * W_ + c2;
        float cp = c0[cidx];
        float cn = sigf(zf) * cp + sigf(zi) * tanhf_(zg);
        c0[cidx] = cn;
        h0w[cidx] = sigf(zo) * tanhf_(cn);
      }
    }
  } else {
    if (k == 0) return;                        // k==0: layer1 has no step
    const int s = k - 1;                       // layer1's time step
    // ---- stage in1: concat(h0@s, h1@s-1), rows own0-1..own0+9, zero-pad
    for (int l = tid; l < 64 * 22; l += 512) {
      int ic = l / 22, rem = l % 22, tr = rem >> 1, c2 = rem & 1;
      int gr = own0 - 1 + tr;
      float v = 0.f;
      if (gr >= 0 && gr < H_)
        v = (ic < HID_) ? h0r[((b * HID_ + ic) * H_ + gr) * W_ + c2]
                        : h1r[((b * HID_ + (ic - HID_)) * H_ + gr) * W_ + c2];
      inb[ic * 24 + c2 * 12 + tr] = v;
    }
    __syncthreads();
    if (rh == 0) convT<64, 0, 5>(inb, W1T, b1[oc], cc, oc, zt);
    else         convT<64, 5, 4>(inb, W1T, b1[oc], cc, oc, zt);
    __syncthreads();
    // ---- gate1: own rows; c1 in-place; capture h_last at s == len-1
    const int len = lens[b];
    for (int it = tid; it < 32 * 18; it += 512) {
      int hid = it & 31, rc = it >> 5;
      int r = rc >> 1, c2 = rc & 1;
      if (r < nz) {
        float zi = zt[c2][r][hid],      zf = zt[c2][r][hid + 32];
        float zo = zt[c2][r][hid + 64], zg = zt[c2][r][hid + 96];
        int cidx = ((b * HID_ + hid) * H_ + own0 + r) * W_ + c2;
        float cp = c1[cidx];
        float cn = sigf(zf) * cp + sigf(zi) * tanhf_(zg);
        float hn = sigf(zo) * tanhf_(cn);
        c1[cidx] = cn;
        h1w[cidx] = hn;
        if (s == len - 1)
          hlast[(b * HID_ + hid) * H_ * W_ + (own0 + r) * W_ + c2] = hn;
      }
    }
  }
}

// nin (1x1 conv over HID) -> fc1 -> fc2. One block per sample.
__global__ __launch_bounds__(256) void head_kernel(
    const float* __restrict__ hlast,
    const float* __restrict__ ninw, const float* __restrict__ ninb,
    const float* __restrict__ FC1T, const float* __restrict__ fc1b,
    const float* __restrict__ fc2w, const float* __restrict__ fc2b,
    float* __restrict__ out)
{
  __shared__ float lin[258];
  __shared__ float o1[256];
  int b = blockIdx.x, tid = threadIdx.x;
  for (int j = tid; j < 258; j += 256) {
    float s = ninb[0];
    #pragma unroll
    for (int h = 0; h < 32; ++h) s = fmaf(ninw[h], hlast[(b * 32 + h) * 258 + j], s);
    lin[j] = s;
  }
  __syncthreads();
  {
    float a = fc1b[tid];
    for (int j = 0; j < 258; ++j) a = fmaf(lin[j], FC1T[j * 256 + tid], a);
    o1[tid] = a;
  }
  __syncthreads();
  if (tid < 2) {
    float s = fc2b[tid];
    for (int k2 = 0; k2 < 256; ++k2) s = fmaf(o1[k2], fc2w[tid * 256 + k2], s);
    out[b * 2 + tid] = s;
  }
}

extern "C" void kernel_launch(void* const* d_in, const int* in_sizes, int n_in,
                              void* d_out, int out_size, void* d_ws, size_t ws_size,
                              hipStream_t stream) {
  const float* x     = (const float*)d_in[0];
  const int*   lens  = (const int*)  d_in[1];
  const float* w0    = (const float*)d_in[2];
  const float* b0    = (const float*)d_in[3];
  const float* w1    = (const float*)d_in[4];
  const float* b1    = (const float*)d_in[5];
  const float* ninw  = (const float*)d_in[6];
  const float* ninb  = (const float*)d_in[7];
  const float* fc1w  = (const float*)d_in[8];
  const float* fc1b  = (const float*)d_in[9];
  const float* fc2w  = (const float*)d_in[10];
  const float* fc2b  = (const float*)d_in[11];
  float* out = (float*)d_out;
  float* ws  = (float*)d_ws;

  const size_t SB = (size_t)SB_;
  // zero region first: h0p1 (read at k=0), h1p1 (read at k=1), c0, c1
  float* h0p1  = ws;
  float* h1p1  = h0p1 + SB;
  float* c0    = h1p1 + SB;
  float* c1    = c0 + SB;
  float* h0p0  = c1 + SB;
  float* h1p0  = h0p0 + SB;
  float* hlast = h1p0 + SB;
  float* W0T   = hlast + SB;               // 36*3*128
  float* W1T   = W0T + 36 * 3 * 128;       // 64*3*128
  float* FC1T  = W1T + 64 * 3 * 128;       // 258*256

  hipMemsetAsync(ws, 0, 4 * SB * sizeof(float), stream);
  init_kernel<<<408, 256, 0, stream>>>(w0, w1, fc1w, W0T, W1T, FC1T);

  // Launch k: layer0 does step k (k<64), layer1 does step k-1 (k>=1).
  // Parity: L0 reads h0p[~k&1], writes h0p[k&1]; L1 reads h1p[k&1], writes h1p[~k&1].
  for (int k = 0; k <= T_; ++k) {
    const float *h0r, *h1r; float *h0w, *h1w;
    if (k & 1) { h0r = h0p0; h0w = h0p1; h1r = h1p1; h1w = h1p0; }
    else       { h0r = h0p1; h0w = h0p0; h1r = h1p0; h1w = h1p1; }
    step_kernel<<<2 * NL_, 512, 0, stream>>>(
        x, lens, W0T, b0, W1T, b1, h0r, h0w, h1r, h1w, c0, c1, hlast, k);
  }

  head_kernel<<<B_, 256, 0, stream>>>(hlast, ninw, ninb, FC1T, fc1b, fc2w, fc2b, out);
}

// Round 7
// 871.484 us; speedup vs baseline: 7.2771x; 1.1040x over previous
//
#include <hip/hip_runtime.h>

#define B_ 16
#define T_ 64
#define C_ 4
#define H_ 129
#define W_ 2
#define HID_ 32
#define R_ 9
#define NCHUNK_ 15                    // ceil(129/9)
#define NL_ (B_*NCHUNK_)              // 240 blocks per layer role
#define SB_ (B_*HID_*H_*W_)           // 132096 floats per state buffer

__device__ __forceinline__ float sigf(float x)   { return 1.0f / (1.0f + __expf(-x)); }
__device__ __forceinline__ float tanhf_(float x) { return 1.0f - 2.0f / (1.0f + __expf(2.0f * x)); }

// Pre-transpose conv weights to [ic][kh][oc] (coalesced per-wave weight loads)
// and fc1_w to [j][o] (coalesced head GEMV).
__global__ __launch_bounds__(256) void init_kernel(
    const float* __restrict__ w0, const float* __restrict__ w1,
    const float* __restrict__ fc1w,
    float* __restrict__ W0T, float* __restrict__ W1T, float* __restrict__ FC1T)
{
  int i = blockIdx.x * 256 + threadIdx.x;
  if (i < 36 * 3 * 128) {
    int ic = i / (3 * 128), kh = (i / 128) % 3, oc = i % 128;
    W0T[i] = w0[(oc * 36 + ic) * 3 + kh];
  }
  int j = i - 36 * 3 * 128;
  if (j >= 0 && j < 64 * 3 * 128) {
    int ic = j / (3 * 128), kh = (j / 128) % 3, oc = j % 128;
    W1T[j] = w1[(oc * 64 + ic) * 3 + kh];
  }
  int k = i - 36 * 3 * 128 - 64 * 3 * 128;
  if (k >= 0 && k < 258 * 256) {
    int jj = k / 256, o = k % 256;
    FC1T[k] = fc1w[o * 258 + jj];
  }
}

// Conv over staged LDS rows (layout [ic][cc][tr], tr stride 12, tr <-> global own0-1+tr),
// ic range [ICB, ICB+NIC), z rows R0..R0+NR-1 (z row r <-> global own0+r; needs tr=r+kh).
// R0==0: inv = floats tr 0..7 -> idx r+kh (max 6). R0==5: inv = tr 4..11 -> idx 1+r+kh.
// Partial sums written to ztp (this ic-half's tile), layout [cc][zr][oc].
template<int ICB, int NIC, int R0, int NR>
__device__ __forceinline__ void convT(
    const float* __restrict__ inb, const float* __restrict__ WT, float bv,
    int cc, int oc, float* __restrict__ ztp)
{
  float acc[NR];
  #pragma unroll
  for (int r = 0; r < NR; ++r) acc[r] = bv;
  #pragma unroll 4
  for (int ic = 0; ic < NIC; ++ic) {
    const float4* p = (const float4*)(inb + (ICB + ic) * 24 + cc * 12);
    float inv[8];
    if (R0 == 0) { *(float4*)&inv[0] = p[0]; *(float4*)&inv[4] = p[1]; }
    else         { *(float4*)&inv[0] = p[1]; *(float4*)&inv[4] = p[2]; }
    const float* wp = WT + (ICB + ic) * 384 + oc;
    #pragma unroll
    for (int kh = 0; kh < 3; ++kh) {
      float w = wp[kh * 128];
      #pragma unroll
      for (int r = 0; r < NR; ++r)
        acc[r] = fmaf(w, inv[(R0 ? 1 : 0) + r + kh], acc[r]);
    }
  }
  #pragma unroll
  for (int r = 0; r < NR; ++r) ztp[cc * 1152 + (R0 + r) * 128 + oc] = acc[r];
}

// Launch k: blocks [0,NL_) = layer0 step k; [NL_,2*NL_) = layer1 step k-1.
// Stream order is the inter-step barrier. 1024 thr: oc(128) x cc(2) x rowhalf(2) x ichalf(2).
// 480 blocks x 16 waves = 7680 waves ~ 94% of device wave slots (2 blocks/CU).
__global__ __launch_bounds__(1024, 8) void step_kernel(
    const float* __restrict__ x, const int* __restrict__ lens,
    const float* __restrict__ W0T, const float* __restrict__ b0,
    const float* __restrict__ W1T, const float* __restrict__ b1,
    const float* __restrict__ h0r, float* __restrict__ h0w,
    const float* __restrict__ h1r, float* __restrict__ h1w,
    float* __restrict__ c0, float* __restrict__ c1,
    float* __restrict__ hlast, int k)
{
  __shared__ float smem[4608 + 1536];   // zt[2ks][2cc][9r][128oc] | inb [ic][cc][12]
  float* zt  = smem;
  float* inb = smem + 4608;

  const int tid  = threadIdx.x;
  const bool isL0 = blockIdx.x < NL_;
  const int lb   = isL0 ? blockIdx.x : blockIdx.x - NL_;
  const int b    = lb / NCHUNK_;
  const int chunk= lb % NCHUNK_;
  const int own0 = chunk * R_;
  const int own1 = min(own0 + R_, H_);
  const int nz   = own1 - own0;
  const int oc   = tid & 127;
  const int cc   = (tid >> 7) & 1;
  const int rh   = (tid >> 8) & 1;      // row-half 0/1
  const int ks   = (tid >> 9) & 1;      // ic-half 0/1

  if (isL0) {
    if (k >= T_) return;                // k==T_: layer0 has no step
    // ---- stage in0: concat(x@k, h0@k-1), rows own0-1..own0+9, float2 over cc
    if (tid < 36 * 11) {
      int ic = tid / 11, tr = tid % 11;
      int gr = own0 - 1 + tr;
      float2 v = make_float2(0.f, 0.f);
      if (gr >= 0 && gr < H_) {
        const float* src = (ic < C_)
          ? &x[((b * T_ + k) * C_ + ic) * (H_ * W_) + gr * W_]
          : &h0r[((b * HID_ + (ic - C_)) * H_ + gr) * W_];
        v = *(const float2*)src;
      }
      inb[ic * 24 + tr]      = v.x;
      inb[ic * 24 + 12 + tr] = v.y;
    }
    __syncthreads();
    {
      float bv = ks ? 0.f : b0[oc];
      float* ztp = zt + ks * 2304;
      if (ks == 0) {
        if (rh == 0) convT< 0, 18, 0, 5>(inb, W0T, bv, cc, oc, ztp);
        else         convT< 0, 18, 5, 4>(inb, W0T, bv, cc, oc, ztp);
      } else {
        if (rh == 0) convT<18, 18, 0, 5>(inb, W0T, bv, cc, oc, ztp);
        else         convT<18, 18, 5, 4>(inb, W0T, bv, cc, oc, ztp);
      }
    }
    __syncthreads();
    // ---- gate0: 32 hid x 9 r x 2 cc = 576 lanes; c0 in-place (thread-local RMW)
    if (tid < 576) {
      int hid = tid & 31, rc = tid >> 5;
      int r = rc >> 1, c2 = rc & 1;
      if (r < nz) {
        int zo_ = c2 * 1152 + r * 128 + hid;
        float zi = zt[zo_]       + zt[2304 + zo_];
        float zf = zt[zo_ + 32]  + zt[2304 + zo_ + 32];
        float zo = zt[zo_ + 64]  + zt[2304 + zo_ + 64];
        float zg = zt[zo_ + 96]  + zt[2304 + zo_ + 96];
        int cidx = ((b * HID_ + hid) * H_ + own0 + r) * W_ + c2;
        float cp = c0[cidx];
        float cn = sigf(zf) * cp + sigf(zi) * tanhf_(zg);
        c0[cidx] = cn;
        h0w[cidx] = sigf(zo) * tanhf_(cn);
      }
    }
  } else {
    if (k == 0) return;                 // k==0: layer1 has no step
    const int s = k - 1;
    // ---- stage in1: concat(h0@s, h1@s-1), rows own0-1..own0+9, float2 over cc
    if (tid < 64 * 11) {
      int ic = tid / 11, tr = tid % 11;
      int gr = own0 - 1 + tr;
      float2 v = make_float2(0.f, 0.f);
      if (gr >= 0 && gr < H_) {
        const float* src = (ic < HID_)
          ? &h0r[((b * HID_ + ic) * H_ + gr) * W_]
          : &h1r[((b * HID_ + (ic - HID_)) * H_ + gr) * W_];
        v = *(const float2*)src;
      }
      inb[ic * 24 + tr]      = v.x;
      inb[ic * 24 + 12 + tr] = v.y;
    }
    __syncthreads();
    {
      float bv = ks ? 0.f : b1[oc];
      float* ztp = zt + ks * 2304;
      if (ks == 0) {
        if (rh == 0) convT< 0, 32, 0, 5>(inb, W1T, bv, cc, oc, ztp);
        else         convT< 0, 32, 5, 4>(inb, W1T, bv, cc, oc, ztp);
      } else {
        if (rh == 0) convT<32, 32, 0, 5>(inb, W1T, bv, cc, oc, ztp);
        else         convT<32, 32, 5, 4>(inb, W1T, bv, cc, oc, ztp);
      }
    }
    __syncthreads();
    // ---- gate1: c1 in-place; capture h_last at s == len-1
    if (tid < 576) {
      int hid = tid & 31, rc = tid >> 5;
      int r = rc >> 1, c2 = rc & 1;
      if (r < nz) {
        int zo_ = c2 * 1152 + r * 128 + hid;
        float zi = zt[zo_]       + zt[2304 + zo_];
        float zf = zt[zo_ + 32]  + zt[2304 + zo_ + 32];
        float zo = zt[zo_ + 64]  + zt[2304 + zo_ + 64];
        float zg = zt[zo_ + 96]  + zt[2304 + zo_ + 96];
        int cidx = ((b * HID_ + hid) * H_ + own0 + r) * W_ + c2;
        float cp = c1[cidx];
        float cn = sigf(zf) * cp + sigf(zi) * tanhf_(zg);
        float hn = sigf(zo) * tanhf_(cn);
        c1[cidx] = cn;
        h1w[cidx] = hn;
        if (s == lens[b] - 1)
          hlast[(b * HID_ + hid) * H_ * W_ + (own0 + r) * W_ + c2] = hn;
      }
    }
  }
}

// nin (1x1 conv over HID) -> fc1 -> fc2. One block per sample.
__global__ __launch_bounds__(256) void head_kernel(
    const float* __restrict__ hlast,
    const float* __restrict__ ninw, const float* __restrict__ ninb,
    const float* __restrict__ FC1T, const float* __restrict__ fc1b,
    const float* __restrict__ fc2w, const float* __restrict__ fc2b,
    float* __restrict__ out)
{
  __shared__ float lin[258];
  __shared__ float o1[256];
  int b = blockIdx.x, tid = threadIdx.x;
  for (int j = tid; j < 258; j += 256) {
    float s = ninb[0];
    #pragma unroll
    for (int h = 0; h < 32; ++h) s = fmaf(ninw[h], hlast[(b * 32 + h) * 258 + j], s);
    lin[j] = s;
  }
  __syncthreads();
  {
    float a = fc1b[tid];
    for (int j = 0; j < 258; ++j) a = fmaf(lin[j], FC1T[j * 256 + tid], a);
    o1[tid] = a;
  }
  __syncthreads();
  if (tid < 2) {
    float s = fc2b[tid];
    for (int k2 = 0; k2 < 256; ++k2) s = fmaf(o1[k2], fc2w[tid * 256 + k2], s);
    out[b * 2 + tid] = s;
  }
}

extern "C" void kernel_launch(void* const* d_in, const int* in_sizes, int n_in,
                              void* d_out, int out_size, void* d_ws, size_t ws_size,
                              hipStream_t stream) {
  const float* x     = (const float*)d_in[0];
  const int*   lens  = (const int*)  d_in[1];
  const float* w0    = (const float*)d_in[2];
  const float* b0    = (const float*)d_in[3];
  const float* w1    = (const float*)d_in[4];
  const float* b1    = (const float*)d_in[5];
  const float* ninw  = (const float*)d_in[6];
  const float* ninb  = (const float*)d_in[7];
  const float* fc1w  = (const float*)d_in[8];
  const float* fc1b  = (const float*)d_in[9];
  const float* fc2w  = (const float*)d_in[10];
  const float* fc2b  = (const float*)d_in[11];
  float* out = (float*)d_out;
  float* ws  = (float*)d_ws;

  const size_t SB = (size_t)SB_;
  // zero region first: h0p1 (read at k=0), h1p1 (read at k=1), c0, c1
  float* h0p1  = ws;
  float* h1p1  = h0p1 + SB;
  float* c0    = h1p1 + SB;
  float* c1    = c0 + SB;
  float* h0p0  = c1 + SB;
  float* h1p0  = h0p0 + SB;
  float* hlast = h1p0 + SB;
  float* W0T   = hlast + SB;               // 36*3*128
  float* W1T   = W0T + 36 * 3 * 128;       // 64*3*128
  float* FC1T  = W1T + 64 * 3 * 128;       // 258*256

  hipMemsetAsync(ws, 0, 4 * SB * sizeof(float), stream);
  init_kernel<<<408, 256, 0, stream>>>(w0, w1, fc1w, W0T, W1T, FC1T);

  // Launch k: layer0 does step k (k<64), layer1 does step k-1 (k>=1).
  for (int k = 0; k <= T_; ++k) {
    const float *h0r, *h1r; float *h0w, *h1w;
    if (k & 1) { h0r = h0p0; h0w = h0p1; h1r = h1p1; h1w = h1p0; }
    else       { h0r = h0p1; h0w = h0p0; h1r = h1p0; h1w = h1p1; }
    step_kernel<<<2 * NL_, 1024, 0, stream>>>(
        x, lens, W0T, b0, W1T, b1, h0r, h0w, h1r, h1w, c0, c1, hlast, k);
  }

  head_kernel<<<B_, 256, 0, stream>>>(hlast, ninw, ninb, FC1T, fc1b, fc2w, fc2b, out);
}